// Round 1
// baseline (256.677 us; speedup 1.0000x reference)
//
#include <hip/hip_runtime.h>
#include <stdint.h>

// SNN readout: h = inputs @ W^T  (bf16 MFMA, fp32->bf16 converted in-kernel),
// then chunked parallel linear scan over T.
//   flt_t = ALPHA*flt_{t-1} + h_t ;  out_t = BETA*out_{t-1} + flt_{t-1}
// Chunk transition is affine: f' = a^L f + lf ; u' = b^L u + wL*f + lu,
// wL = (a^L - b^L)/(a-b). Three passes: local states -> combine -> final scan.

#define ALPHA 0.95f
#define BETA  0.9f

constexpr int Bdim = 64, T = 1000, Idim = 512, Odim = 256;
constexpr int M = Bdim * T;         // 64000 rows
constexpr int BM = 128, BN = 128, BK = 32;
constexpr int C = 8, L = 125;       // T = C*L
constexpr int BO = Bdim * Odim;     // 16384 independent sequences

typedef short bf16x8 __attribute__((ext_vector_type(8)));   // 8 bf16 (4 VGPRs), per guide
typedef float f32x4  __attribute__((ext_vector_type(4)));

// round-to-nearest-even fp32 -> bf16, packed pair into one u32
__device__ inline uint32_t pk_bf16(float a, float b) {
  union { float f; uint32_t u; } x, y; x.f = a; y.f = b;
  uint32_t lo = (x.u + 0x7FFFu + ((x.u >> 16) & 1u)) >> 16;
  uint32_t hi = (y.u + 0x7FFFu + ((y.u >> 16) & 1u)) & 0xFFFF0000u;
  return lo | hi;
}
__device__ inline uint16_t f2bf(float a) {
  union { float f; uint32_t u; } x; x.f = a;
  return (uint16_t)((x.u + 0x7FFFu + ((x.u >> 16) & 1u)) >> 16);
}
__device__ inline float bf2f(uint16_t h) {
  union { uint32_t u; float f; } x; x.u = ((uint32_t)h) << 16;
  return x.f;
}

// ---------------- GEMM: H[m][n] = sum_k A[m][k] * W[n][k], bf16 MFMA ----------------
__global__ __launch_bounds__(256) void gemm_h(const float* __restrict__ A,
                                              const float* __restrict__ W,
                                              uint16_t* __restrict__ H) {
  // LDS tiles, bf16, padded row stride 40 (80B, keeps 16B alignment for b128 reads)
  __shared__ uint16_t As[128][40];
  __shared__ uint16_t Bs[128][40];

  const int tid  = threadIdx.x;
  const int lane = tid & 63;
  const int wave = tid >> 6;          // 4 waves
  const int wm   = (wave >> 1) * 64;  // wave's m-offset in tile
  const int wn   = (wave & 1) * 64;   // wave's n-offset in tile
  const int l15  = lane & 15;
  const int quad = lane >> 4;
  const int rm   = blockIdx.x * BM;   // 500 blocks
  const int cn   = blockIdx.y * BN;   // 2 blocks

  const int sr = tid >> 3;            // staging row 0..31 (x4 passes)
  const int sc = (tid & 7) * 4;       // staging col 0..28

  f32x4 acc[4][4] = {};

  for (int k0 = 0; k0 < Idim; k0 += BK) {
    __syncthreads();
#pragma unroll
    for (int p = 0; p < 4; ++p) {
      int r = p * 32 + sr;
      const float4 av = *(const float4*)&A[(size_t)(rm + r) * Idim + k0 + sc];
      const float4 bv = *(const float4*)&W[(size_t)(cn + r) * Idim + k0 + sc];
      uint2 ap = make_uint2(pk_bf16(av.x, av.y), pk_bf16(av.z, av.w));
      uint2 bp = make_uint2(pk_bf16(bv.x, bv.y), pk_bf16(bv.z, bv.w));
      *(uint2*)&As[r][sc] = ap;
      *(uint2*)&Bs[r][sc] = bp;
    }
    __syncthreads();

    bf16x8 af[4], bfq[4];
#pragma unroll
    for (int mt = 0; mt < 4; ++mt)
      af[mt] = *(const bf16x8*)&As[wm + mt * 16 + l15][quad * 8];
#pragma unroll
    for (int nt = 0; nt < 4; ++nt)
      bfq[nt] = *(const bf16x8*)&Bs[wn + nt * 16 + l15][quad * 8];
#pragma unroll
    for (int mt = 0; mt < 4; ++mt)
#pragma unroll
      for (int nt = 0; nt < 4; ++nt)
        acc[mt][nt] = __builtin_amdgcn_mfma_f32_16x16x32_bf16(af[mt], bfq[nt], acc[mt][nt], 0, 0, 0);
  }

  // epilogue: C/D layout col = lane&15, row = quad*4 + reg (verified m89)
#pragma unroll
  for (int mt = 0; mt < 4; ++mt) {
#pragma unroll
    for (int nt = 0; nt < 4; ++nt) {
#pragma unroll
      for (int r = 0; r < 4; ++r) {
        int gm = rm + wm + mt * 16 + quad * 4 + r;
        int gn = cn + wn + nt * 16 + l15;
        H[(size_t)gm * Odim + gn] = f2bf(acc[mt][nt][r]);
      }
    }
  }
}

// ---------------- pass 1: per-chunk local scan (zero init) -> final (lf, lu) --------
__global__ __launch_bounds__(256) void scan_local(const uint16_t* __restrict__ H,
                                                  float2* __restrict__ St) {
  const int b = blockIdx.x >> 3;   // / C
  const int c = blockIdx.x & 7;
  const int o = threadIdx.x;
  const uint16_t* hp = H + ((size_t)(b * T + c * L)) * Odim + o;
  float f = 0.f, u = 0.f;
#pragma unroll 5
  for (int j = 0; j < L; ++j) {
    float hv = bf2f(hp[(size_t)j * Odim]);
    float nu = BETA * u + f;     // uses OLD f
    f = ALPHA * f + hv;
    u = nu;
  }
  St[c * BO + b * Odim + o] = make_float2(f, u);
}

// ---------------- pass 2: sequential combine over the C chunk states ----------------
constexpr double dpow(double x, int n) { double r = 1.0; for (int i = 0; i < n; ++i) r *= x; return r; }

__global__ __launch_bounds__(256) void scan_combine(const float2* __restrict__ St,
                                                    float2* __restrict__ Init) {
  constexpr float AL = (float)dpow(0.95, L);
  constexpr float BL = (float)dpow(0.90, L);
  constexpr float WL = (float)((dpow(0.95, L) - dpow(0.90, L)) / (0.95 - 0.90));
  const int i = blockIdx.x * 256 + threadIdx.x;   // over B*O
  float f = 0.f, u = 0.f;
#pragma unroll
  for (int c = 0; c < C; ++c) {
    Init[c * BO + i] = make_float2(f, u);
    float2 s = St[c * BO + i];
    float nf = AL * f + s.x;
    float nu = BL * u + WL * f + s.y;
    f = nf; u = nu;
  }
}

// ---------------- pass 3: final scan with correct chunk-init, write outputs ---------
__global__ __launch_bounds__(256) void scan_final(const uint16_t* __restrict__ H,
                                                  const float2* __restrict__ Init,
                                                  float* __restrict__ Out) {
  const int b = blockIdx.x >> 3;
  const int c = blockIdx.x & 7;
  const int o = threadIdx.x;
  const size_t base = ((size_t)(b * T + c * L)) * Odim + o;
  const uint16_t* hp = H + base;
  float* op = Out + base;
  float2 s = Init[c * BO + b * Odim + o];
  float f = s.x, u = s.y;
#pragma unroll 5
  for (int j = 0; j < L; ++j) {
    float hv = bf2f(hp[(size_t)j * Odim]);
    float nu = BETA * u + f;     // out_t = beta*out + old flt
    op[(size_t)j * Odim] = nu;
    f = ALPHA * f + hv;
    u = nu;
  }
}

extern "C" void kernel_launch(void* const* d_in, const int* in_sizes, int n_in,
                              void* d_out, int out_size, void* d_ws, size_t ws_size,
                              hipStream_t stream) {
  const float* A = (const float*)d_in[0];   // (B, T, I) fp32
  const float* W = (const float*)d_in[1];   // (O, I) fp32
  float* Out = (float*)d_out;               // (B, T, O) fp32

  // workspace layout: H (bf16, M*O) | St (C*BO float2) | Init (C*BO float2)
  uint16_t* H = (uint16_t*)d_ws;
  const size_t hbytes = (size_t)M * Odim * sizeof(uint16_t);   // 32.77 MB
  float2* St   = (float2*)((char*)d_ws + hbytes);
  float2* Init = St + (size_t)C * BO;

  dim3 g1(M / BM, Odim / BN);               // 500 x 2
  gemm_h<<<g1, 256, 0, stream>>>(A, W, H);
  scan_local<<<Bdim * C, 256, 0, stream>>>(H, St);
  scan_combine<<<BO / 256, 256, 0, stream>>>(St, Init);
  scan_final<<<Bdim * C, 256, 0, stream>>>(H, Init, Out);
}

// Round 2
// 250.136 us; speedup vs baseline: 1.0261x; 1.0261x over previous
//
#include <hip/hip_runtime.h>
#include <stdint.h>

// SNN readout: h = inputs @ W^T (bf16 MFMA, fp32->bf16 converted in-kernel),
// then chunked parallel linear scan over T.
//   flt_t = ALPHA*flt_{t-1} + h_t ;  out_t = BETA*out_{t-1} + flt_{t-1}
// R2: GEMM with register-prefetch double buffering + XOR-swizzled unpadded
// bf16 LDS (bank-uniform b128 reads/writes). Scans: 4 o's/thread, C=40.

#define ALPHA 0.95f
#define BETA  0.9f

constexpr int Bdim = 64, T = 1000, Idim = 512, Odim = 256;
constexpr int M = Bdim * T;         // 64000 rows
constexpr int C = 40, L = 25;       // T = C*L
constexpr int BO = Bdim * Odim;     // 16384 independent sequences

typedef short bf16x8 __attribute__((ext_vector_type(8)));   // 8 bf16 (4 VGPRs)
typedef float f32x4  __attribute__((ext_vector_type(4)));

// round-to-nearest-even fp32 -> bf16, packed pair into one u32
__device__ inline uint32_t pk_bf16(float a, float b) {
  union { float f; uint32_t u; } x, y; x.f = a; y.f = b;
  uint32_t lo = (x.u + 0x7FFFu + ((x.u >> 16) & 1u)) >> 16;
  uint32_t hi = (y.u + 0x7FFFu + ((y.u >> 16) & 1u)) & 0xFFFF0000u;
  return lo | hi;
}
__device__ inline uint16_t f2bf(float a) {
  union { float f; uint32_t u; } x; x.f = a;
  return (uint16_t)((x.u + 0x7FFFu + ((x.u >> 16) & 1u)) >> 16);
}
__device__ inline float bf2f(uint16_t h) {
  union { uint32_t u; float f; } x; x.u = ((uint32_t)h) << 16;
  return x.f;
}

// ---------------- GEMM: H[m][n] = sum_k A[m][k] * W[n][k], bf16 MFMA ----------------
// Tile 128x128, BK=32. LDS layout: row-major 128 rows x 32 bf16 (64B rows, no pad),
// 16B chunk c of row r stored at chunk position (c ^ (r&3)) -> bank-uniform b128.
__global__ __launch_bounds__(256) void gemm_h(const float* __restrict__ A,
                                              const float* __restrict__ W,
                                              uint16_t* __restrict__ H) {
  __shared__ uint16_t As[128 * 32];
  __shared__ uint16_t Bs[128 * 32];

  const int tid  = threadIdx.x;
  const int lane = tid & 63;
  const int wave = tid >> 6;          // 4 waves
  const int wm   = (wave >> 1) * 64;
  const int wn   = (wave & 1) * 64;
  const int l15  = lane & 15;
  const int quad = lane >> 4;
  const int rm   = blockIdx.x * 128;  // 500
  const int cn   = blockIdx.y * 128;  // 2

  // staging: thread -> (row = p*64 + tid>>2, chunk = tid&3), chunk = 8 bf16 = 16B
  const int srow = tid >> 2;          // 0..63
  const int sc   = tid & 3;
  int soff[2];
#pragma unroll
  for (int p = 0; p < 2; ++p) {
    int row = p * 64 + srow;
    soff[p] = row * 32 + ((sc ^ (row & 3)) * 8);
  }
  const float* aB0 = A + (size_t)(rm + srow) * Idim + sc * 8;
  const float* aB1 = A + (size_t)(rm + 64 + srow) * Idim + sc * 8;
  const float* bB0 = W + (size_t)(cn + srow) * Idim + sc * 8;
  const float* bB1 = W + (size_t)(cn + 64 + srow) * Idim + sc * 8;

  // fragment read offsets (uint16 units): row*32 + (quad ^ (row&3))*8 ; row&3 == l15&3
  const int swz = (quad ^ (l15 & 3)) * 8;
  int aoff[4], boff[4];
#pragma unroll
  for (int t = 0; t < 4; ++t) {
    aoff[t] = (wm + t * 16 + l15) * 32 + swz;
    boff[t] = (wn + t * 16 + l15) * 32 + swz;
  }

  f32x4 acc[4][4] = {};

  float4 ra0 = *(const float4*)(aB0),     ra1 = *(const float4*)(aB0 + 4);
  float4 ra2 = *(const float4*)(aB1),     ra3 = *(const float4*)(aB1 + 4);
  float4 rb0 = *(const float4*)(bB0),     rb1 = *(const float4*)(bB0 + 4);
  float4 rb2 = *(const float4*)(bB1),     rb3 = *(const float4*)(bB1 + 4);

  for (int k0 = 0; k0 < Idim; k0 += 32) {
    __syncthreads();   // previous iter's fragment reads complete
    *(uint4*)&As[soff[0]] = make_uint4(pk_bf16(ra0.x, ra0.y), pk_bf16(ra0.z, ra0.w),
                                       pk_bf16(ra1.x, ra1.y), pk_bf16(ra1.z, ra1.w));
    *(uint4*)&As[soff[1]] = make_uint4(pk_bf16(ra2.x, ra2.y), pk_bf16(ra2.z, ra2.w),
                                       pk_bf16(ra3.x, ra3.y), pk_bf16(ra3.z, ra3.w));
    *(uint4*)&Bs[soff[0]] = make_uint4(pk_bf16(rb0.x, rb0.y), pk_bf16(rb0.z, rb0.w),
                                       pk_bf16(rb1.x, rb1.y), pk_bf16(rb1.z, rb1.w));
    *(uint4*)&Bs[soff[1]] = make_uint4(pk_bf16(rb2.x, rb2.y), pk_bf16(rb2.z, rb2.w),
                                       pk_bf16(rb3.x, rb3.y), pk_bf16(rb3.z, rb3.w));
    if (k0 + 32 < Idim) {   // prefetch next tile; latency hides under MFMA phase
      int kn = k0 + 32;
      ra0 = *(const float4*)(aB0 + kn); ra1 = *(const float4*)(aB0 + kn + 4);
      ra2 = *(const float4*)(aB1 + kn); ra3 = *(const float4*)(aB1 + kn + 4);
      rb0 = *(const float4*)(bB0 + kn); rb1 = *(const float4*)(bB0 + kn + 4);
      rb2 = *(const float4*)(bB1 + kn); rb3 = *(const float4*)(bB1 + kn + 4);
    }
    __syncthreads();   // stores visible

    bf16x8 af[4], bfq[4];
#pragma unroll
    for (int t = 0; t < 4; ++t) af[t]  = *(const bf16x8*)&As[aoff[t]];
#pragma unroll
    for (int t = 0; t < 4; ++t) bfq[t] = *(const bf16x8*)&Bs[boff[t]];
#pragma unroll
    for (int mt = 0; mt < 4; ++mt)
#pragma unroll
      for (int nt = 0; nt < 4; ++nt)
        acc[mt][nt] = __builtin_amdgcn_mfma_f32_16x16x32_bf16(af[mt], bfq[nt], acc[mt][nt], 0, 0, 0);
  }

  // epilogue: C/D layout col = lane&15, row = quad*4 + reg
#pragma unroll
  for (int mt = 0; mt < 4; ++mt)
#pragma unroll
    for (int nt = 0; nt < 4; ++nt)
#pragma unroll
      for (int r = 0; r < 4; ++r) {
        int gm = rm + wm + mt * 16 + quad * 4 + r;
        int gn = cn + wn + nt * 16 + l15;
        H[(size_t)gm * Odim + gn] = f2bf(acc[mt][nt][r]);
      }
}

// ---------------- pass 1: per-chunk local scan (zero init) -> (lf, lu) --------------
// one wave per (b,c); each lane handles 4 consecutive o's (8B H loads)
__global__ __launch_bounds__(256) void scan_local(const uint16_t* __restrict__ H,
                                                  float2* __restrict__ St) {
  const int pair = blockIdx.x * 4 + (threadIdx.x >> 6);
  const int b = pair / C, c = pair % C;
  const int lane = threadIdx.x & 63;
  const ushort4* hp = (const ushort4*)(H + (size_t)(b * T + c * L) * Odim) + lane;
  float f[4] = {}, u[4] = {};
#pragma unroll
  for (int j = 0; j < L; ++j) {
    ushort4 hv = hp[j * 64];
    float h0 = bf2f(hv.x), h1 = bf2f(hv.y), h2 = bf2f(hv.z), h3 = bf2f(hv.w);
    float n0 = BETA * u[0] + f[0]; f[0] = ALPHA * f[0] + h0; u[0] = n0;
    float n1 = BETA * u[1] + f[1]; f[1] = ALPHA * f[1] + h1; u[1] = n1;
    float n2 = BETA * u[2] + f[2]; f[2] = ALPHA * f[2] + h2; u[2] = n2;
    float n3 = BETA * u[3] + f[3]; f[3] = ALPHA * f[3] + h3; u[3] = n3;
  }
  float2* sp = &St[(size_t)c * BO + b * Odim + lane * 4];
#pragma unroll
  for (int i = 0; i < 4; ++i) sp[i] = make_float2(f[i], u[i]);
}

// ---------------- pass 2: sequential combine over the C chunk states ----------------
constexpr double dpow(double x, int n) { double r = 1.0; for (int i = 0; i < n; ++i) r *= x; return r; }

__global__ __launch_bounds__(256) void scan_combine(const float2* __restrict__ St,
                                                    float2* __restrict__ Init) {
  constexpr float AL = (float)dpow(0.95, L);
  constexpr float BL = (float)dpow(0.90, L);
  constexpr float WL = (float)((dpow(0.95, L) - dpow(0.90, L)) / (0.95 - 0.90));
  const int i = blockIdx.x * 256 + threadIdx.x;   // over B*O
  float f = 0.f, u = 0.f;
#pragma unroll
  for (int c = 0; c < C; ++c) {
    Init[(size_t)c * BO + i] = make_float2(f, u);
    float2 s = St[(size_t)c * BO + i];
    float nf = AL * f + s.x;
    float nu = BL * u + WL * f + s.y;
    f = nf; u = nu;
  }
}

// ---------------- pass 3: final scan with chunk-init, write outputs -----------------
__global__ __launch_bounds__(256) void scan_final(const uint16_t* __restrict__ H,
                                                  const float2* __restrict__ Init,
                                                  float* __restrict__ Out) {
  const int pair = blockIdx.x * 4 + (threadIdx.x >> 6);
  const int b = pair / C, c = pair % C;
  const int lane = threadIdx.x & 63;
  const size_t base = (size_t)(b * T + c * L) * Odim;
  const ushort4* hp = (const ushort4*)(H + base) + lane;
  float4* op = (float4*)(Out + base) + lane;
  const float2* sp = &Init[(size_t)c * BO + b * Odim + lane * 4];
  float f[4], u[4];
#pragma unroll
  for (int i = 0; i < 4; ++i) { float2 s = sp[i]; f[i] = s.x; u[i] = s.y; }
#pragma unroll
  for (int j = 0; j < L; ++j) {
    ushort4 hv = hp[j * 64];
    float h0 = bf2f(hv.x), h1 = bf2f(hv.y), h2 = bf2f(hv.z), h3 = bf2f(hv.w);
    float4 o4;
    o4.x = BETA * u[0] + f[0]; f[0] = ALPHA * f[0] + h0; u[0] = o4.x;
    o4.y = BETA * u[1] + f[1]; f[1] = ALPHA * f[1] + h1; u[1] = o4.y;
    o4.z = BETA * u[2] + f[2]; f[2] = ALPHA * f[2] + h2; u[2] = o4.z;
    o4.w = BETA * u[3] + f[3]; f[3] = ALPHA * f[3] + h3; u[3] = o4.w;
    op[j * 64] = o4;
  }
}

extern "C" void kernel_launch(void* const* d_in, const int* in_sizes, int n_in,
                              void* d_out, int out_size, void* d_ws, size_t ws_size,
                              hipStream_t stream) {
  const float* A = (const float*)d_in[0];   // (B, T, I) fp32
  const float* W = (const float*)d_in[1];   // (O, I) fp32
  float* Out = (float*)d_out;               // (B, T, O) fp32

  // workspace: H (bf16, M*O = 32.8MB) | St (C*BO float2, 5.2MB) | Init (5.2MB)
  uint16_t* H = (uint16_t*)d_ws;
  const size_t hbytes = (size_t)M * Odim * sizeof(uint16_t);
  float2* St   = (float2*)((char*)d_ws + hbytes);
  float2* Init = St + (size_t)C * BO;

  dim3 g1(M / 128, Odim / 128);             // 500 x 2
  gemm_h<<<g1, 256, 0, stream>>>(A, W, H);
  scan_local<<<Bdim * C / 4, 256, 0, stream>>>(H, St);
  scan_combine<<<BO / 256, 256, 0, stream>>>(St, Init);
  scan_final<<<Bdim * C / 4, 256, 0, stream>>>(H, Init, Out);
}